// Round 12
// baseline (217.364 us; speedup 1.0000x reference)
//
#include <hip/hip_runtime.h>
#include <math.h>

#define NROWS 65536
#define DDIM  256
#define KCODES 1024
// pack geometry (inherited 32-code super-chunk layout)
#define PK_KSTEPS 16
#define PK_CODES 32
#define PL_B (PK_KSTEPS * 2 * PK_CODES * 16)   // 16384 plane bytes per 32-code chunk
#define CH_B (2 * PL_B)                        // 32768 bytes (hi+lo)
// argmin: 16-code chunks
#define CH16 16
#define NCH16 (KCODES / CH16)      // 64
#define CH16_B 16384               // 16 codes x 256 d x 2B x 2 planes
#define RPB 128                    // rows per block (4 waves x 32 rows)
#define GRID_ARG (NROWS / RPB)     // 512

typedef _Float16 half8 __attribute__((ext_vector_type(8)));
typedef float    f32x4  __attribute__((ext_vector_type(4)));

// ws layout (bytes):
//   [0,       262144)  idx       int32[65536]   (fallback path only)
//   [262144,  266240)  enorm_lin f32[1024]
//   [266240,  270336)  counts    int32[1024]
//   [270336,  532480)  partials  f32[65536]
//   [532480, 1581056)  pack      (fused path only; else pack lives in out region)
#define PACK_WS_OFF 532480
#define WS_NEED_FUSED 1581056
#define PACK_F 16777220            // fallback: pack inside encodings out-region

// ---------------- prep: pack emb into fragment-ready f16 hi/lo planes ----------------
__global__ __launch_bounds__(256) void pack_emb_kernel(const float* __restrict__ emb,
                                                       char* __restrict__ pack) {
    int tid  = blockIdx.x * 256 + threadIdx.x;   // 32768 threads
    int code = tid >> 5;
    int g    = tid & 31;                          // d0 = g*8 = ks*16 + kh*8
    int ks = g >> 1, kh = g & 1;
    int c = code >> 5, ci = code & 31;
    const float* src = emb + (size_t)code * DDIM + g * 8;
    half8 hi, lo;
#pragma unroll
    for (int j = 0; j < 8; ++j) {
        float v = src[j];
        _Float16 h = (_Float16)v;
        hi[j] = h;
        lo[j] = (_Float16)(v - (float)h);
    }
    size_t off = (size_t)c * CH_B + (size_t)ks * 1024 + (size_t)kh * 512 + (size_t)ci * 16;
    *(half8*)(pack + off) = hi;
    *(half8*)(pack + off + PL_B) = lo;
}

__global__ __launch_bounds__(256) void norm_emb_kernel(const float* __restrict__ emb,
                                                       float* __restrict__ enorm_lin,
                                                       int* __restrict__ counts) {
    int w = threadIdx.x >> 6, lane = threadIdx.x & 63;
    int code = blockIdx.x * 4 + w;                // grid 256 -> 1024 codes
    float4 v = *(const float4*)(emb + (size_t)code * DDIM + lane * 4);
    float s = v.x * v.x + v.y * v.y + v.z * v.z + v.w * v.w;
    for (int off = 32; off; off >>= 1) s += __shfl_down(s, off, 64);
    if (lane == 0) enorm_lin[code] = -0.5f * s;
    if (blockIdx.x == 0)
        for (int i = threadIdx.x; i < KCODES; i += 256) counts[i] = 0;
}

// ---------------- argmin: 32 rows/wave (2 B-sets share every a-frag read) ----------------
// FUSED=true additionally writes quantized/encodings/partials/counts (epilogue fused).
template <bool FUSED>
__global__ __launch_bounds__(256, 2) void argmin_k(const float* __restrict__ x,
                                                   const char* __restrict__ pack,
                                                   const float* __restrict__ enorm_lin,
                                                   const float* __restrict__ emb,
                                                   float* __restrict__ out,
                                                   float* __restrict__ partials,
                                                   int* __restrict__ counts,
                                                   int* __restrict__ outidx) {
    __shared__ char smem[2 * CH16_B];
    const int tid  = threadIdx.x;
    const int lane = tid & 63;
    const int w    = __builtin_amdgcn_readfirstlane(tid >> 6);   // 0..3
    const int l15  = lane & 15;
    const int g4   = lane >> 4;
    const int base_w = blockIdx.x * RPB + w * 32;   // 32 rows per wave
    const int row0 = base_w + l15;
    const int row1 = row0 + 16;

    char* buf0 = smem;
    char* buf1 = smem + CH16_B;

#define ISSUE_DMA16(cidx, dst)                                                            \
    do {                                                                                  \
        const char* _s0 = pack + (size_t)((cidx) >> 1) * CH_B + ((cidx) & 1) * 256        \
                          + l15 * 16;                                                     \
        char* _dst = (dst);                                                               \
        for (int i = w; i < 16; i += 4) {                                                 \
            int b = i * 4 + g4;                                                           \
            int pl = b >> 5, k16 = (b >> 1) & 15, khh = b & 1;                            \
            __builtin_amdgcn_global_load_lds(                                             \
                (const __attribute__((address_space(1))) void*)(_s0 + (size_t)pl * PL_B + k16 * 1024 + khh * 512), \
                (__attribute__((address_space(3))) void*)(_dst + i * 1024), 16, 0, 0);    \
        }                                                                                 \
    } while (0)

    ISSUE_DMA16(0, buf0);
    ISSUE_DMA16(1, buf1);

    // Two B-frag sets: rows row0 (set0) and row1 (set1), f16 hi/lo split.
    half8 bh0[8], bl0[8], bh1[8], bl1[8];
#pragma unroll
    for (int s = 0; s < 8; ++s) {
        const float* p0 = x + (size_t)row0 * DDIM + s * 32 + g4 * 8;
        const float* p1 = x + (size_t)row1 * DDIM + s * 32 + g4 * 8;
        float4 a0 = *(const float4*)p0;
        float4 a1 = *(const float4*)(p0 + 4);
        float4 c0 = *(const float4*)p1;
        float4 c1 = *(const float4*)(p1 + 4);
        float v0[8] = {a0.x, a0.y, a0.z, a0.w, a1.x, a1.y, a1.z, a1.w};
        float v1[8] = {c0.x, c0.y, c0.z, c0.w, c1.x, c1.y, c1.z, c1.w};
#pragma unroll
        for (int j = 0; j < 8; ++j) {
            _Float16 h0 = (_Float16)v0[j];
            bh0[s][j] = h0;
            bl0[s][j] = (_Float16)(v0[j] - (float)h0);
            _Float16 h1 = (_Float16)v1[j];
            bh1[s][j] = h1;
            bl1[s][j] = (_Float16)(v1[j] - (float)h1);
        }
    }

    float bestv0 = -3.4e38f, bestv1 = -3.4e38f;
    int   besti0 = 0,        besti1 = 0;

    for (int c = 0; c < NCH16; ++c) {
        if (c == NCH16 - 1) asm volatile("s_waitcnt vmcnt(0)" ::: "memory");
        else                 asm volatile("s_waitcnt vmcnt(4)" ::: "memory");
        __builtin_amdgcn_s_barrier();

        char* buf = (c & 1) ? buf1 : buf0;

        float4 erv = *(const float4*)(enorm_lin + c * 16 + g4 * 4);
        float er[4] = {erv.x, erv.y, erv.z, erv.w};

        // 6 independent chains: each a-frag pair feeds both row-sets
        f32x4 a0A = (f32x4)0.0f, a0B = (f32x4)0.0f, a0C = (f32x4)0.0f;
        f32x4 a1A = (f32x4)0.0f, a1B = (f32x4)0.0f, a1C = (f32x4)0.0f;
#pragma unroll
        for (int s = 0; s < 8; ++s) {
            half8 ah = *(const half8*)(buf + s * 1024 + lane * 16);
            half8 al = *(const half8*)(buf + 8192 + s * 1024 + lane * 16);
            a0A = __builtin_amdgcn_mfma_f32_16x16x32_f16(ah, bh0[s], a0A, 0, 0, 0);
            a1A = __builtin_amdgcn_mfma_f32_16x16x32_f16(ah, bh1[s], a1A, 0, 0, 0);
            a0B = __builtin_amdgcn_mfma_f32_16x16x32_f16(ah, bl0[s], a0B, 0, 0, 0);
            a1B = __builtin_amdgcn_mfma_f32_16x16x32_f16(ah, bl1[s], a1B, 0, 0, 0);
            a0C = __builtin_amdgcn_mfma_f32_16x16x32_f16(al, bh0[s], a0C, 0, 0, 0);
            a1C = __builtin_amdgcn_mfma_f32_16x16x32_f16(al, bh1[s], a1C, 0, 0, 0);
        }

        int cb0 = c * CH16 + g4 * 4;
#pragma unroll
        for (int r = 0; r < 4; ++r) {
            float v0 = a0A[r] + a0B[r] + a0C[r] + er[r];
            float v1 = a1A[r] + a1B[r] + a1C[r] + er[r];
            int co = cb0 + r;
            if (v0 > bestv0) { bestv0 = v0; besti0 = co; }
            if (v1 > bestv1) { bestv1 = v1; besti1 = co; }
        }

        __builtin_amdgcn_s_barrier();
        if (c + 2 < NCH16) ISSUE_DMA16(c + 2, buf);
    }
#undef ISSUE_DMA16

    // combine the 4 k-groups (xor16 merges g4 0<->1,2<->3; xor32 merges pairs)
#pragma unroll
    for (int m = 16; m <= 32; m <<= 1) {
        float pv = __shfl_xor(bestv0, m, 64);
        int   pi = __shfl_xor(besti0, m, 64);
        if (pv > bestv0 || (pv == bestv0 && pi < besti0)) { bestv0 = pv; besti0 = pi; }
        pv = __shfl_xor(bestv1, m, 64);
        pi = __shfl_xor(besti1, m, 64);
        if (pv > bestv1 || (pv == bestv1 && pi < besti1)) { bestv1 = pv; besti1 = pi; }
    }

    if (!FUSED) {
        if (lane < 16) {
            outidx[base_w + lane]      = besti0;
            outidx[base_w + 16 + lane] = besti1;
        }
        return;
    }

    // ---------- fused epilogue: this wave writes its 32 rows ----------
    for (int rr = 0; rr < 32; ++rr) {
        int rowr = base_w + rr;
        int bi = (rr < 16) ? __shfl(besti0, rr, 64) : __shfl(besti1, rr - 16, 64);
        int sbi = __builtin_amdgcn_readfirstlane(bi);

        const float* xr = x + (size_t)rowr * DDIM + lane * 4;
        const float* qr = emb + (size_t)sbi * DDIM + lane * 4;
        float4 xv = *(const float4*)xr;
        float4 qv = *(const float4*)qr;
        float4 df = {qv.x - xv.x, qv.y - xv.y, qv.z - xv.z, qv.w - xv.w};

        // quantized_st = x + (q - x), scalar stores (base offset out+1 is 4B-aligned only)
        float* qd = out + 1 + (size_t)rowr * DDIM + lane * 4;
        qd[0] = xv.x + df.x;
        qd[1] = xv.y + df.y;
        qd[2] = xv.z + df.z;
        qd[3] = xv.w + df.w;

        // per-row sum of squared diff -> partials
        float ss = df.x * df.x + df.y * df.y + df.z * df.z + df.w * df.w;
        for (int off = 32; off; off >>= 1) ss += __shfl_down(ss, off, 64);
        if (lane == 0) {
            partials[rowr] = ss;
            atomicAdd(&counts[sbi], 1);
        }

        // encodings row: 8 float2 stores per lane (even-d offsets are 8B-aligned)
        float* encr = out + 16777218 + (size_t)rowr * KCODES;
#pragma unroll
        for (int j = 0; j < 8; ++j) {
            int d0 = 2 * (lane + 64 * j);
            float2 v;
            v.x = (sbi == d0)     ? 1.f : 0.f;
            v.y = (sbi == d0 + 1) ? 1.f : 0.f;
            *(float2*)(encr + d0) = v;
        }
    }
}

// ---------------- fallback epilogue (unfused path only) ----------------
__global__ __launch_bounds__(256) void epilogue_kernel(const float* __restrict__ x,
                                                       const float* __restrict__ emb,
                                                       const int* __restrict__ idxbuf,
                                                       float* __restrict__ out,
                                                       float* __restrict__ partials,
                                                       int* __restrict__ counts) {
    int row = blockIdx.x;
    int t   = threadIdx.x;
    int idx = idxbuf[row];

    float q  = emb[(size_t)idx * DDIM + t];
    float xv = x[(size_t)row * DDIM + t];

    float diff = q - xv;
    out[1 + (size_t)row * DDIM + t] = xv + diff;

    float* enc = out + 16777218 + (size_t)row * KCODES;
    int base = t * 4;
    float2 z0 = {0.f, 0.f}, z1 = {0.f, 0.f};
    int r = idx - base;
    if (r == 0) z0.x = 1.f;
    else if (r == 1) z0.y = 1.f;
    else if (r == 2) z1.x = 1.f;
    else if (r == 3) z1.y = 1.f;
    *(float2*)(enc + base)     = z0;
    *(float2*)(enc + base + 2) = z1;

    float s = diff * diff;
    for (int off = 32; off; off >>= 1) s += __shfl_down(s, off, 64);
    __shared__ float ps[4];
    if ((t & 63) == 0) ps[t >> 6] = s;
    __syncthreads();
    if (t == 0) partials[row] = ps[0] + ps[1] + ps[2] + ps[3];
    if (t == 1) atomicAdd(&counts[idx], 1);
}

__global__ __launch_bounds__(1024) void finalize_kernel(const float* __restrict__ partials,
                                                        const int* __restrict__ counts,
                                                        float* __restrict__ out) {
    __shared__ double sd[16];
    int t = threadIdx.x;

    double s = 0.0;
    for (int i = t; i < NROWS; i += 1024) s += (double)partials[i];
    for (int off = 32; off; off >>= 1) s += __shfl_down(s, off, 64);
    if ((t & 63) == 0) sd[t >> 6] = s;
    __syncthreads();
    if (t == 0) {
        double tot = 0.0;
        for (int wv = 0; wv < 16; ++wv) tot += sd[wv];
        double mse = tot / ((double)NROWS * (double)DDIM);
        out[0] = (float)(1.25 * mse);
    }
    __syncthreads();

    double h;
    {
        int c = counts[t];
        float p = (float)c / (float)NROWS;
        float term = p * logf(p + 1e-10f);
        h = (double)term;
    }
    for (int off = 32; off; off >>= 1) h += __shfl_down(h, off, 64);
    if ((t & 63) == 0) sd[t >> 6] = h;
    __syncthreads();
    if (t == 0) {
        double tot = 0.0;
        for (int wv = 0; wv < 16; ++wv) tot += sd[wv];
        out[16777217] = expf((float)(-tot));
    }
}

extern "C" void kernel_launch(void* const* d_in, const int* in_sizes, int n_in,
                              void* d_out, int out_size, void* d_ws, size_t ws_size,
                              hipStream_t stream) {
    const float* x   = (const float*)d_in[0];
    const float* emb = (const float*)d_in[1];
    float* out = (float*)d_out;
    char* ws = (char*)d_ws;

    int*   idx       = (int*)ws;
    float* enorm_lin = (float*)(ws + 262144);
    int*   counts    = (int*)(ws + 266240);
    float* partials  = (float*)(ws + 270336);

    const bool fused = (ws_size >= (size_t)WS_NEED_FUSED);
    char* pack = fused ? (ws + PACK_WS_OFF) : (char*)(out + PACK_F);

    pack_emb_kernel<<<128, 256, 0, stream>>>(emb, pack);
    norm_emb_kernel<<<256, 256, 0, stream>>>(emb, enorm_lin, counts);

    if (fused) {
        argmin_k<true><<<GRID_ARG, 256, 0, stream>>>(x, pack, enorm_lin, emb, out,
                                                     partials, counts, idx);
    } else {
        argmin_k<false><<<GRID_ARG, 256, 0, stream>>>(x, pack, enorm_lin, emb, out,
                                                      partials, counts, idx);
        epilogue_kernel<<<NROWS, 256, 0, stream>>>(x, emb, idx, out, partials, counts);
    }
    finalize_kernel<<<1, 1024, 0, stream>>>(partials, counts, out);
}

// Round 14
// 209.100 us; speedup vs baseline: 1.0395x; 1.0395x over previous
//
#include <hip/hip_runtime.h>
#include <math.h>

#define NROWS 65536
#define DDIM  256
#define KCODES 1024
// pack geometry (inherited 32-code super-chunk layout)
#define PL_B 16384                 // plane bytes per 32-code chunk
#define CH_B (2 * PL_B)            // 32768 bytes (hi+lo)
// argmin: 16-code chunks
#define CH16 16
#define NCH16 (KCODES / CH16)      // 64
#define CH16_B 16384               // 16 codes x 256 d x 2B x 2 planes

typedef _Float16 half8 __attribute__((ext_vector_type(8)));
typedef float    f32x4  __attribute__((ext_vector_type(4)));
typedef float    f32x2  __attribute__((ext_vector_type(2)));

// ws layout (bytes):
//   [262144,  266240)  enorm_lin f32[1024]
//   [266240,  270336)  counts    int32[1024]
//   [270336,  532480)  partials  f32[65536]
//   [532480, 1581056)  pack
#define PACK_WS_OFF 532480
#define ENC_F 16777218             // encodings base (float index in out)

// ---------------- prep: pack emb into fragment-ready f16 hi/lo planes ----------------
__global__ __launch_bounds__(256) void pack_emb_kernel(const float* __restrict__ emb,
                                                       char* __restrict__ pack) {
    int tid  = blockIdx.x * 256 + threadIdx.x;   // 32768 threads
    int code = tid >> 5;
    int g    = tid & 31;                          // d0 = g*8 = ks*16 + kh*8
    int ks = g >> 1, kh = g & 1;
    int c = code >> 5, ci = code & 31;
    const float* src = emb + (size_t)code * DDIM + g * 8;
    half8 hi, lo;
#pragma unroll
    for (int j = 0; j < 8; ++j) {
        float v = src[j];
        _Float16 h = (_Float16)v;
        hi[j] = h;
        lo[j] = (_Float16)(v - (float)h);
    }
    size_t off = (size_t)c * CH_B + (size_t)ks * 1024 + (size_t)kh * 512 + (size_t)ci * 16;
    *(half8*)(pack + off) = hi;
    *(half8*)(pack + off + PL_B) = lo;
}

__global__ __launch_bounds__(256) void norm_emb_kernel(const float* __restrict__ emb,
                                                       float* __restrict__ enorm_lin,
                                                       int* __restrict__ counts) {
    int w = threadIdx.x >> 6, lane = threadIdx.x & 63;
    int code = blockIdx.x * 4 + w;                // grid 256 -> 1024 codes
    float4 v = *(const float4*)(emb + (size_t)code * DDIM + lane * 4);
    float s = v.x * v.x + v.y * v.y + v.z * v.z + v.w * v.w;
    for (int off = 32; off; off >>= 1) s += __shfl_down(s, off, 64);
    if (lane == 0) enorm_lin[code] = -0.5f * s;
    if (blockIdx.x == 0)
        for (int i = threadIdx.x; i < KCODES; i += 256) counts[i] = 0;
}

// ---------------- fused: argmin (round-11 geometry) + zero-stream + register epilogue ----------------
__global__ __launch_bounds__(256, 4) void argmin_fused(const float* __restrict__ x,
                                                       const char* __restrict__ pack,
                                                       const float* __restrict__ enorm_lin,
                                                       const float* __restrict__ emb,
                                                       float* __restrict__ out,
                                                       float* __restrict__ partials,
                                                       int* __restrict__ counts) {
    __shared__ char smem[2 * CH16_B];
    const int tid  = threadIdx.x;
    const int lane = tid & 63;
    const int w    = __builtin_amdgcn_readfirstlane(tid >> 6);   // 0..3
    const int l15  = lane & 15;
    const int g4   = lane >> 4;
    const int base = blockIdx.x * 64 + w * 16;   // 64 rows/block, 16 rows/wave
    const int row  = base + l15;

    char* buf0 = smem;
    char* buf1 = smem + CH16_B;

    // this block's 64 encodings rows: 65536 floats starting at enc0 (enc0 == 2 mod 4)
    float* enc0 = out + ENC_F + (size_t)blockIdx.x * 64 * KCODES;

#define ISSUE_DMA16(cidx, dst)                                                            \
    do {                                                                                  \
        const char* _s0 = pack + (size_t)((cidx) >> 1) * CH_B + ((cidx) & 1) * 256        \
                          + l15 * 16;                                                     \
        char* _dst = (dst);                                                               \
        for (int i = w; i < 16; i += 4) {                                                 \
            int b = i * 4 + g4;                                                           \
            int pl = b >> 5, k16 = (b >> 1) & 15, khh = b & 1;                            \
            __builtin_amdgcn_global_load_lds(                                             \
                (const __attribute__((address_space(1))) void*)(_s0 + (size_t)pl * PL_B + k16 * 1024 + khh * 512), \
                (__attribute__((address_space(3))) void*)(_dst + i * 1024), 16, 0, 0);    \
        }                                                                                 \
    } while (0)

    ISSUE_DMA16(0, buf0);
    ISSUE_DMA16(1, buf1);

    // B-frags: lane l holds x[row = base + (l&15)][d = 32s + (l>>4)*8 + j], f16 hi/lo
    half8 bh[8], bl[8];
#pragma unroll
    for (int s = 0; s < 8; ++s) {
        const float* p = x + (size_t)row * DDIM + s * 32 + g4 * 8;
        float4 v0 = *(const float4*)p;
        float4 v1 = *(const float4*)(p + 4);
        float vv[8] = {v0.x, v0.y, v0.z, v0.w, v1.x, v1.y, v1.z, v1.w};
#pragma unroll
        for (int j = 0; j < 8; ++j) {
            _Float16 h = (_Float16)vv[j];
            bh[s][j] = h;
            bl[s][j] = (_Float16)(vv[j] - (float)h);
        }
    }

    float bestv = -3.4e38f;
    int   besti = 0;
    const f32x4 z4 = (f32x4)0.0f;
    const f32x2 z2 = (f32x2)0.0f;

    for (int c = 0; c < NCH16; ++c) {
        if (c == NCH16 - 1) asm volatile("s_waitcnt vmcnt(0)" ::: "memory");
        else                 asm volatile("s_waitcnt vmcnt(4)" ::: "memory");
        __builtin_amdgcn_s_barrier();

        char* buf = (c & 1) ? buf1 : buf0;

        float4 erv = *(const float4*)(enorm_lin + c * 16 + g4 * 4);
        float er[4] = {erv.x, erv.y, erv.z, erv.w};

        f32x4 accA = (f32x4)0.0f;
        f32x4 accB = (f32x4)0.0f;
        f32x4 accC = (f32x4)0.0f;
#pragma unroll
        for (int s = 0; s < 8; ++s) {
            half8 ah = *(const half8*)(buf + s * 1024 + lane * 16);
            half8 al = *(const half8*)(buf + 8192 + s * 1024 + lane * 16);
            accA = __builtin_amdgcn_mfma_f32_16x16x32_f16(ah, bh[s], accA, 0, 0, 0);
            accB = __builtin_amdgcn_mfma_f32_16x16x32_f16(ah, bl[s], accB, 0, 0, 0);
            accC = __builtin_amdgcn_mfma_f32_16x16x32_f16(al, bh[s], accC, 0, 0, 0);
        }

        int cb0 = c * CH16 + g4 * 4;
#pragma unroll
        for (int r = 0; r < 4; ++r) {
            float v = accA[r] + accB[r] + accC[r] + er[r];
            int co = cb0 + r;
            if (v > bestv) { bestv = v; besti = co; }
        }

        // zero-stream: this block's encodings rows, 4KB/chunk, nontemporal
        {
            int slot = c * 256 + tid;
            if (slot < 16383) {
                __builtin_nontemporal_store(z4, (f32x4*)(enc0 + 2 + slot * 4));
            } else {   // last slot: 2-float head + 2-float tail (enc0 is 8B-aligned)
                __builtin_nontemporal_store(z2, (f32x2*)(enc0));
                __builtin_nontemporal_store(z2, (f32x2*)(enc0 + 65534));
            }
        }

        __builtin_amdgcn_s_barrier();
        if (c + 2 < NCH16) ISSUE_DMA16(c + 2, buf);
    }
#undef ISSUE_DMA16

    // combine the 4 k-groups (all 4 g4-lanes of a row end with identical best)
#pragma unroll
    for (int m = 16; m <= 32; m <<= 1) {
        float pv = __shfl_xor(bestv, m, 64);
        int   pi = __shfl_xor(besti, m, 64);
        if (pv > bestv || (pv == bestv && pi < besti)) { bestv = pv; besti = pi; }
    }

    // order all zero-stores before the ones/quant writes
    asm volatile("s_waitcnt vmcnt(0)" ::: "memory");
    __syncthreads();

    // ---------- register epilogue ----------
    const int b = besti;                       // this lane's row result
    if (g4 == 0)
        __builtin_nontemporal_store(1.0f, out + ENC_F + (size_t)row * KCODES + b);

    const float* qrow = emb + (size_t)b * DDIM;
    float* qd = out + 1 + (size_t)row * DDIM;
    float ss = 0.f;
#pragma unroll
    for (int s = 0; s < 8; ++s) {
        int d0 = s * 32 + g4 * 8;
        float4 q0 = *(const float4*)(qrow + d0);
        float4 q1 = *(const float4*)(qrow + d0 + 4);
        float qv[8] = {q0.x, q0.y, q0.z, q0.w, q1.x, q1.y, q1.z, q1.w};
#pragma unroll
        for (int j = 0; j < 8; ++j) {
            float xv = (float)bh[s][j] + (float)bl[s][j];   // x' (err ~5e-7 abs)
            float df = qv[j] - xv;
            __builtin_nontemporal_store(xv + df, qd + d0 + j);
            ss += df * df;
        }
    }
    // sum ss over the 4 g4-lanes of this row
    ss += __shfl_xor(ss, 16, 64);
    ss += __shfl_xor(ss, 32, 64);
    if (g4 == 0) {
        partials[row] = ss;
        atomicAdd(&counts[b], 1);
    }
}

// ---------------- finalize ----------------
__global__ __launch_bounds__(1024) void finalize_kernel(const float* __restrict__ partials,
                                                        const int* __restrict__ counts,
                                                        float* __restrict__ out) {
    __shared__ double sd[16];
    int t = threadIdx.x;

    double s = 0.0;
    for (int i = t; i < NROWS; i += 1024) s += (double)partials[i];
    for (int off = 32; off; off >>= 1) s += __shfl_down(s, off, 64);
    if ((t & 63) == 0) sd[t >> 6] = s;
    __syncthreads();
    if (t == 0) {
        double tot = 0.0;
        for (int wv = 0; wv < 16; ++wv) tot += sd[wv];
        double mse = tot / ((double)NROWS * (double)DDIM);
        out[0] = (float)(1.25 * mse);
    }
    __syncthreads();

    double h;
    {
        int c = counts[t];
        float p = (float)c / (float)NROWS;
        float term = p * logf(p + 1e-10f);
        h = (double)term;
    }
    for (int off = 32; off; off >>= 1) h += __shfl_down(h, off, 64);
    if ((t & 63) == 0) sd[t >> 6] = h;
    __syncthreads();
    if (t == 0) {
        double tot = 0.0;
        for (int wv = 0; wv < 16; ++wv) tot += sd[wv];
        out[16777217] = expf((float)(-tot));
    }
}

extern "C" void kernel_launch(void* const* d_in, const int* in_sizes, int n_in,
                              void* d_out, int out_size, void* d_ws, size_t ws_size,
                              hipStream_t stream) {
    const float* x   = (const float*)d_in[0];
    const float* emb = (const float*)d_in[1];
    float* out = (float*)d_out;
    char* ws = (char*)d_ws;

    float* enorm_lin = (float*)(ws + 262144);
    int*   counts    = (int*)(ws + 266240);
    float* partials  = (float*)(ws + 270336);
    char*  pack      = ws + PACK_WS_OFF;     // ws_size >= 1.59 MB (verified round 12)

    pack_emb_kernel<<<128, 256, 0, stream>>>(emb, pack);
    norm_emb_kernel<<<256, 256, 0, stream>>>(emb, enorm_lin, counts);
    argmin_fused<<<NROWS / 64, 256, 0, stream>>>(x, pack, enorm_lin, emb, out,
                                                 partials, counts);
    finalize_kernel<<<1, 1024, 0, stream>>>(partials, counts, out);
}